// Round 2
// 164.487 us; speedup vs baseline: 1.0008x; 1.0008x over previous
//
#include <hip/hip_runtime.h>

// SoftAttentionAlignment B=8, L=2048, D=128 fp32. MFMA flash attention, both dirs.
// R7 (resubmit; previous round was an infra failure, no signal):
// (1) swapped QK^T (mfma(K,Q) -> S^T) so P lives in registers; PV A-fragment
//     assembled via v_cvt_pk_bf16_f32 + v_permlane32_swap + v_permlane16_swap.
//     sP buffer deleted (was 8 b16 scatter writes + 1 b128 read per thread-tile).
// (2) V^T bf16 LDS: row stride 144 B + 64 B swizzle on d-bit3 -> staging scatter
//     writes conflict-free (was 4-way), fragment reads stay uniform & 16B-aligned.
// (3) async-stage split: global loads for tile t+1 issued after barrier B of tile t,
//     converted+written at top of t+1 -> HBM/L2 latency hidden under QK+PV MFMA.
// Block = 512 thr = 8 waves; group g = wv>>2 owns j in [g*1024, g*1024+1024),
// 32 tiles of TJ=32 for the same 64 q-rows; partial (O,l) merged via LDS at end.

typedef __bf16    bf16;
typedef _Float16  f16;
typedef __bf16    bf16x8 __attribute__((ext_vector_type(8)));
typedef _Float16  f16x8  __attribute__((ext_vector_type(8)));
typedef float     floatx4 __attribute__((ext_vector_type(4)));
typedef unsigned int uintx4 __attribute__((ext_vector_type(4)));

#define NB 8
#define SL 2048
#define TI 64

#define SKV_S  136   // f16 elems per j-row (272 B = 17*16: uniform bank slots)
#define SVT_S  72    // bf16 elems per d-row (144 B = 9*16) + 32-elem swizzle on d bit3

// per-group LDS: sKV [32][136] f16 = 8704 B ; sVT [128][72] bf16 = 18432 B
#define GSPAN    27136
#define OFF_VT   8704
#define OFF_L    54272           // float[64]
#define LDS_BYTES 54528          // aOut fp32 [64][132] = 33792 overlaps group buffers

__global__ __launch_bounds__(512, 4)
void soft_attn_align_mfma(const float* __restrict__ x1,
                          const float* __restrict__ x2,
                          float* __restrict__ out)
{
    __shared__ char lds_raw[LDS_BYTES];

    const int tid  = threadIdx.x;
    const int lane = tid & 63;
    const int wv   = tid >> 6;          // 0..7
    const int g    = wv >> 2;           // j-half group
    const int rowbase = (wv & 3) * 16;  // wave's 16 q-rows within the 64-row tile
    const int lr   = lane & 15;
    const int lq   = lane >> 4;
    const int t256 = tid & 255;         // thread id within group

    char* gb   = lds_raw + g * GSPAN;
    f16*   sKV  = (f16*) (gb);             // [32][136] fp16 row-major (j, d)
    bf16*  sVT  = (bf16*)(gb + OFF_VT);    // [128][72] bf16 d-major (d, j), swizzled
    float* aOut = (float*)(lds_raw);       // [64][132] fp32 (epilogue/combine)
    float* sL   = (float*)(lds_raw + OFF_L);

    const int i0  = blockIdx.x * TI;
    const int bi  = blockIdx.y;
    const int dir = blockIdx.z;

    const float* xq  = dir ? x2 : x1;
    const float* xkv = dir ? x1 : x2;

    // ---- Q fragments (fp16) into registers, once ----
    f16x8 aQ[4];
    {
        const float* qrow = xq + ((size_t)bi * SL + i0 + rowbase + lr) * 128;
        #pragma unroll
        for (int kk = 0; kk < 4; ++kk) {
            const float4* src = (const float4*)(qrow + kk * 32 + lq * 8);
            float4 va = src[0], vb = src[1];
            float v[8] = {va.x, va.y, va.z, va.w, vb.x, vb.y, vb.z, vb.w};
            f16x8 f;
            #pragma unroll
            for (int i = 0; i < 8; ++i) f[i] = (f16)v[i];
            aQ[kk] = f;
        }
    }

    float   l_acc = 0.0f;
    floatx4 Oacc[8];
    #pragma unroll
    for (int nd = 0; nd < 8; ++nd) Oacc[nd] = (floatx4){0.f, 0.f, 0.f, 0.f};

    // staging assignment: same row r_st, two col-chunks cp = c0, c0+8
    const int r_st = t256 & 31;
    const int c0   = t256 >> 5;          // 0..7
    const float* kvbase = xkv + ((size_t)bi * SL + g * 1024 + r_st) * 128;

    float4 ld[2][2];
    {   // prologue: load tile 0
        const float4* s0 = (const float4*)(kvbase + c0 * 8);
        ld[0][0] = s0[0]; ld[0][1] = s0[1];
        const float4* s1 = (const float4*)(kvbase + (c0 + 8) * 8);
        ld[1][0] = s1[0]; ld[1][1] = s1[1];
    }

    for (int t = 0; t < 32; ++t) {
        __syncthreads();   // (A) prev tile's fragment reads done before restage

        // ---- convert + write staged regs (tile t) ----
        #pragma unroll
        for (int k = 0; k < 2; ++k) {
            const int cp = c0 + 8 * k;
            float4 va = ld[k][0], vb = ld[k][1];
            float v[8] = {va.x, va.y, va.z, va.w, vb.x, vb.y, vb.z, vb.w};
            f16x8 f;
            #pragma unroll
            for (int i = 0; i < 8; ++i) f[i] = (f16)v[i];
            *(f16x8*)(sKV + r_st * SKV_S + cp * 8) = f;
            const int vbase = cp * 8 * SVT_S + r_st + 32 * (c0 & 1);
            #pragma unroll
            for (int i = 0; i < 8; ++i)
                sVT[vbase + i * SVT_S] = (bf16)v[i];
        }
        __syncthreads();   // (B) tile t staged

        // ---- issue global loads for tile t+1 (land under the MFMA work) ----
        if (t < 31) {
            const float* kb = kvbase + (size_t)(t + 1) * 32 * 128;
            const float4* s0 = (const float4*)(kb + c0 * 8);
            ld[0][0] = s0[0]; ld[0][1] = s0[1];
            const float4* s1 = (const float4*)(kb + (c0 + 8) * 8);
            ld[1][0] = s1[0]; ld[1][1] = s1[1];
        }

        // ---- S^T = K . Q^T : lane holds S[i = rowbase+lr][j = 16f + 4lq + r] ----
        floatx4 Sf0 = (floatx4){0.f, 0.f, 0.f, 0.f};
        floatx4 Sf1 = (floatx4){0.f, 0.f, 0.f, 0.f};
        #pragma unroll
        for (int kk = 0; kk < 4; ++kk) {
            f16x8 aK0 = *(const f16x8*)(sKV + (lr)      * SKV_S + kk * 32 + lq * 8);
            f16x8 aK1 = *(const f16x8*)(sKV + (16 + lr) * SKV_S + kk * 32 + lq * 8);
            Sf0 = __builtin_amdgcn_mfma_f32_16x16x32_f16(aK0, aQ[kk], Sf0, 0, 0, 0);
            Sf1 = __builtin_amdgcn_mfma_f32_16x16x32_f16(aK1, aQ[kk], Sf1, 0, 0, 0);
        }

        // ---- p = exp(S); pack bf16 pairs; permlane-redistribute into PV A-frag ----
        float p00 = __expf(Sf0[0]), p01 = __expf(Sf0[1]);
        float p02 = __expf(Sf0[2]), p03 = __expf(Sf0[3]);
        float p10 = __expf(Sf1[0]), p11 = __expf(Sf1[1]);
        float p12 = __expf(Sf1[2]), p13 = __expf(Sf1[3]);
        l_acc += ((p00 + p01) + (p02 + p03)) + ((p10 + p11) + (p12 + p13));

        unsigned int A0, B0, A1, B1;
        asm("v_cvt_pk_bf16_f32 %0, %1, %2" : "=v"(A0) : "v"(p00), "v"(p01));
        asm("v_cvt_pk_bf16_f32 %0, %1, %2" : "=v"(B0) : "v"(p02), "v"(p03));
        asm("v_cvt_pk_bf16_f32 %0, %1, %2" : "=v"(A1) : "v"(p10), "v"(p11));
        asm("v_cvt_pk_bf16_f32 %0, %1, %2" : "=v"(B1) : "v"(p12), "v"(p13));
        // lane group needs f = g>>1 from source groups {2(g&1), 2(g&1)+1}:
        asm("v_permlane32_swap_b32 %0, %1" : "+v"(A0), "+v"(A1));
        asm("v_permlane16_swap_b32 %0, %1" : "+v"(A0), "+v"(A1));  // A0=d0, A1=d2
        asm("v_permlane32_swap_b32 %0, %1" : "+v"(B0), "+v"(B1));
        asm("v_permlane16_swap_b32 %0, %1" : "+v"(B0), "+v"(B1));  // B0=d1, B1=d3
        uintx4 fr; fr.x = A0; fr.y = B0; fr.z = A1; fr.w = B1;
        bf16x8 aP = __builtin_bit_cast(bf16x8, fr);

        // ---- O += P . V  (K = 32 -> single kstep) ----
        const int voff = lq * 8 + 32 * ((lr >> 3) & 1);
        #pragma unroll
        for (int nd = 0; nd < 8; ++nd) {
            bf16x8 bV = *(const bf16x8*)(sVT + (nd * 16 + lr) * SVT_S + voff);
            Oacc[nd] = __builtin_amdgcn_mfma_f32_16x16x32_bf16(aP, bV, Oacc[nd], 0, 0, 0);
        }
    }

    // ---- row sums: lane holds partial for i = lr; sum across lq groups ----
    l_acc += __shfl_xor(l_acc, 16, 64);
    l_acc += __shfl_xor(l_acc, 32, 64);
    // redistribute to Oacc row alignment (row = rowbase + lq*4 + r)
    float l_row[4];
    #pragma unroll
    for (int r = 0; r < 4; ++r)
        l_row[r] = __shfl(l_acc, lq * 4 + r, 64);

    __syncthreads();   // all tile-buffer reads done before combine overwrites LDS

    // ---- combine j-halves: group 1 publishes partials, group 0 merges+normalizes ----
    if (g == 1) {
        #pragma unroll
        for (int r = 0; r < 4; ++r) {
            int row = rowbase + lq * 4 + r;
            #pragma unroll
            for (int nd = 0; nd < 8; ++nd)
                aOut[row * 132 + nd * 16 + lr] = Oacc[nd][r];
            if (lr == 0) sL[row] = l_row[r];
        }
    }
    __syncthreads();
    if (g == 0) {
        #pragma unroll
        for (int r = 0; r < 4; ++r) {
            int row = rowbase + lq * 4 + r;
            float inv = 1.0f / (l_row[r] + sL[row]);
            #pragma unroll
            for (int nd = 0; nd < 8; ++nd) {
                int idx = row * 132 + nd * 16 + lr;
                aOut[idx] = (Oacc[nd][r] + aOut[idx]) * inv;
            }
        }
    }
    __syncthreads();

    // ---- epilogue: out row = [q, A, q-A, q*A], q exact fp32 from global ----
    float* outb = out + ((size_t)dir * NB * SL + (size_t)bi * SL + i0) * 512;
    #pragma unroll
    for (int k = 0; k < 4; ++k) {
        int s = tid + 512 * k;          // 2048 slots: row (0..63), c4 (0..31)
        int r = s >> 5, c4 = s & 31;
        float4 a = *(const float4*)(aOut + r * 132 + c4 * 4);
        float4 q = *(const float4*)(xq + ((size_t)bi * SL + i0 + r) * 128 + c4 * 4);
        float4 d, m;
        d.x = q.x - a.x; d.y = q.y - a.y; d.z = q.z - a.z; d.w = q.w - a.w;
        m.x = q.x * a.x; m.y = q.y * a.y; m.z = q.z * a.z; m.w = q.w * a.w;
        float4* orow = (float4*)(outb + (size_t)r * 512);
        orow[c4]      = q;
        orow[32 + c4] = a;
        orow[64 + c4] = d;
        orow[96 + c4] = m;
    }
}

extern "C" void kernel_launch(void* const* d_in, const int* in_sizes, int n_in,
                              void* d_out, int out_size, void* d_ws, size_t ws_size,
                              hipStream_t stream) {
    const float* x1 = (const float*)d_in[0];
    const float* x2 = (const float*)d_in[1];
    float* out = (float*)d_out;
    (void)d_ws; (void)ws_size; (void)in_sizes; (void)n_in; (void)out_size;

    dim3 grid(SL / TI, NB, 2);
    dim3 block(512);
    soft_attn_align_mfma<<<grid, block, 0, stream>>>(x1, x2, out);
}